// Round 13
// baseline (142.834 us; speedup 1.0000x reference)
//
#include <hip/hip_runtime.h>
#include <hip/hip_bf16.h>

// 3D bilateral filter, radius 2 (125 taps), input (2,1,128,128,128) f32.
// v13: y-pair coarsening. v12 closed the cycle model (scalar VALU 2 cyc,
// cvt 4, exp 9, VOP3P 4 at ~1.6 GHz sustained): taps 96k cyc/SIMD of 126k
// wall; the slack is row overhead + DS pressure + stalls. Each thread now
// owns TWO y-rows (4 voxels each): every LDS row read serves 40 taps (dy
// windows of y and y+1 overlap), halving DS reads/row-addressing/row-const
// work per tap. Tile 16x16x8, LDS 20x20x12=18.75 KB; grid = 2048 blocks =
// exactly 8 blocks/CU -> full residency, no tail.
// Tap unchanged (v11-verified): sub, fma(t,-t,CC), saturating v_cvt_u32_f32,
// add, fma. Tile pre-scaled by sR; OOB sentinel -> -inf -> cvt -> w=+0.

#define RADIUS 2
#define N 128
#define TX 16
#define TY 16                         // 2 y per thread
#define TZ 8
#define PITCH (TX + 2 * RADIUS)       // 20
#define LYD (TY + 2 * RADIUS)         // 20
#define LZD (TZ + 2 * RADIUS)         // 12
#define LDS_SIZE (PITCH * LYD * LZD)  // 4800 floats = 18.75 KB

#define LOG2E 1.4426950408889634f
#define BIG 1.0e18f
#define EXP2_SCALE 8388608.0f         // 2^23
#define EXP2_BIAS 1065353216.0f       // 127 * 2^23

__global__ __launch_bounds__(256, 4) void bilateral3d_kernel(
    const float* __restrict__ in, const float* __restrict__ p_sx,
    const float* __restrict__ p_sy, const float* __restrict__ p_sz,
    const float* __restrict__ p_cs, float* __restrict__ out) {
  __shared__ float s[LDS_SIZE];

  const int tid = threadIdx.x;
  const int x0 = blockIdx.x * TX;
  const int y0 = blockIdx.y * TY;
  const int zb = blockIdx.z;  // low 4 bits = z-tile, bit 4 = batch
  const int z0 = (zb & 15) * TZ;
  const int b = zb >> 4;

  const float sxv = p_sx[0], syv = p_sy[0], szv = p_sz[0], csv = p_cs[0];
  const float AX2 = EXP2_SCALE * LOG2E / (2.0f * sxv * sxv);
  const float AY2 = EXP2_SCALE * LOG2E / (2.0f * syv * syv);
  const float AZ2 = EXP2_SCALE * LOG2E / (2.0f * szv * szv);
  const float AX2_4 = 4.0f * AX2;
  const float py1 = AY2, py4 = 4.0f * AY2;
  const float sR = __builtin_sqrtf(EXP2_SCALE * LOG2E / (2.0f * csv * csv));

  const float* vol = in + (size_t)b * (N * N * N);

  // --- stage 20x20x12 halo tile, PRE-SCALED by sR (OOB -> sentinel) ---
  for (int i = tid; i < LDS_SIZE; i += 256) {
    int lx = i % PITCH;
    int t = i / PITCH;
    int ly = t % LYD;
    int lz = t / LYD;
    int gx = x0 + lx - RADIUS;
    int gy = y0 + ly - RADIUS;
    int gz = z0 + lz - RADIUS;
    float v = BIG;
    if ((unsigned)gx < N && (unsigned)gy < N && (unsigned)gz < N)
      v = vol[((size_t)gz * N + gy) * N + gx];
    s[i] = v * sR;
  }
  __syncthreads();

  const int ty = tid & 7;          // y-pair index: rows 2ty, 2ty+1
  const int tx = (tid >> 3) & 3;   // x-group: voxels x0+4tx .. x0+4tx+3
  const int tz = tid >> 5;

  const int xw = 4 * tx;
  const int yc = 2 * ty + RADIUS;  // local row of first owned y

  // centers (scaled): two rows
  const int cbA = ((tz + RADIUS) * LYD + yc) * PITCH + xw;
  const float4 CAa = *(const float4*)&s[cbA];
  const float4 CBa = *(const float4*)&s[cbA + 4];
  const float xca0 = CAa.z, xca1 = CAa.w, xca2 = CBa.x, xca3 = CBa.y;
  const float4 CAb = *(const float4*)&s[cbA + PITCH];
  const float4 CBb = *(const float4*)&s[cbA + PITCH + 4];
  const float xcb0 = CAb.z, xcb1 = CAb.w, xcb2 = CBb.x, xcb3 = CBb.y;

  float na0 = 0, na1 = 0, na2 = 0, na3 = 0;
  float ea0 = 0, ea1 = 0, ea2 = 0, ea3 = 0;
  float nb0 = 0, nb1 = 0, nb2 = 0, nb3 = 0;
  float eb0 = 0, eb1 = 0, eb2 = 0, eb3 = 0;

  // scalar Schraudolph tap: 5 insts
#define TAP(XC, FV, CC, NN, DD)                          \
  {                                                      \
    float _t = (XC) - (FV);                              \
    float _f = fmaf(_t, -_t, (CC));                      \
    unsigned _q;                                         \
    asm("v_cvt_u32_f32 %0, %1" : "=v"(_q) : "v"(_f));    \
    float _w = __uint_as_float(_q);                      \
    DD += _w;                                            \
    NN = fmaf(_w, (FV), NN);                             \
  }

  // 20 taps of one center-row (suffix S = a|b) against the loaded row
#define DOROW(S, PY)                                     \
  {                                                      \
    const float cc0 = bz - (PY);                         \
    const float cm1 = cc0 - AX2;                         \
    const float cm4 = cc0 - AX2_4;                       \
    TAP(xc##S##0, f0, cm4, n##S##0, e##S##0)             \
    TAP(xc##S##1, f1, cm4, n##S##1, e##S##1)             \
    TAP(xc##S##2, f2, cm4, n##S##2, e##S##2)             \
    TAP(xc##S##3, f3, cm4, n##S##3, e##S##3)             \
    TAP(xc##S##0, f1, cm1, n##S##0, e##S##0)             \
    TAP(xc##S##1, f2, cm1, n##S##1, e##S##1)             \
    TAP(xc##S##2, f3, cm1, n##S##2, e##S##2)             \
    TAP(xc##S##3, f4, cm1, n##S##3, e##S##3)             \
    TAP(xc##S##0, f2, cc0, n##S##0, e##S##0)             \
    TAP(xc##S##1, f3, cc0, n##S##1, e##S##1)             \
    TAP(xc##S##2, f4, cc0, n##S##2, e##S##2)             \
    TAP(xc##S##3, f5, cc0, n##S##3, e##S##3)             \
    TAP(xc##S##0, f3, cm1, n##S##0, e##S##0)             \
    TAP(xc##S##1, f4, cm1, n##S##1, e##S##1)             \
    TAP(xc##S##2, f5, cm1, n##S##2, e##S##2)             \
    TAP(xc##S##3, f6, cm1, n##S##3, e##S##3)             \
    TAP(xc##S##0, f4, cm4, n##S##0, e##S##0)             \
    TAP(xc##S##1, f5, cm4, n##S##1, e##S##1)             \
    TAP(xc##S##2, f6, cm4, n##S##2, e##S##2)             \
    TAP(xc##S##3, f7, cm4, n##S##3, e##S##3)             \
  }

#define LOADROW(J)                                                \
    const int rb = (zrow + yc + (J)) * PITCH + xw;                \
    const float4 A = *(const float4*)&s[rb];                      \
    const float4 B = *(const float4*)&s[rb + 4];                  \
    const float f0 = A.x, f1 = A.y, f2 = A.z, f3 = A.w;           \
    const float f4 = B.x, f5 = B.y, f6 = B.z, f7 = B.w;

#pragma unroll 1
  for (int dz = -RADIUS; dz <= RADIUS; ++dz) {
    const float bz = EXP2_BIAS - AZ2 * (float)(dz * dz);
    const int zrow = (tz + RADIUS + dz) * LYD;

    { LOADROW(-2) DOROW(a, py4) }                 // dya=-2
    { LOADROW(-1) DOROW(a, py1) DOROW(b, py4) }   // dya=-1, dyb=-2
    { LOADROW(0)  DOROW(a, 0.0f) DOROW(b, py1) }  // dya= 0, dyb=-1
    { LOADROW(1)  DOROW(a, py1) DOROW(b, 0.0f) }  // dya=+1, dyb= 0
    { LOADROW(2)  DOROW(a, py4) DOROW(b, py1) }   // dya=+2, dyb=+1
    { LOADROW(3)  DOROW(b, py4) }                 // dyb=+2
  }

  // values were pre-scaled by sR: out = num / (den * sR)
  const int gz = z0 + tz;
  const int gya = y0 + 2 * ty;
  float4 ra, rbv;
  ra.x = na0 / (ea0 * sR);
  ra.y = na1 / (ea1 * sR);
  ra.z = na2 / (ea2 * sR);
  ra.w = na3 / (ea3 * sR);
  rbv.x = nb0 / (eb0 * sR);
  rbv.y = nb1 / (eb1 * sR);
  rbv.z = nb2 / (eb2 * sR);
  rbv.w = nb3 / (eb3 * sR);

  float* op = &out[(((size_t)b * N + gz) * N + gya) * N + (x0 + xw)];
  *(float4*)op = ra;
  *(float4*)(op + N) = rbv;
}

extern "C" void kernel_launch(void* const* d_in, const int* in_sizes, int n_in,
                              void* d_out, int out_size, void* d_ws, size_t ws_size,
                              hipStream_t stream) {
  const float* in = (const float*)d_in[0];
  const float* sx = (const float*)d_in[1];
  const float* sy = (const float*)d_in[2];
  const float* sz = (const float*)d_in[3];
  const float* cs = (const float*)d_in[4];
  float* out = (float*)d_out;

  dim3 grid(N / TX, N / TY, (N / TZ) * 2);  // 8 x 8 x 32 = 2048 blocks
  bilateral3d_kernel<<<grid, 256, 0, stream>>>(in, sx, sy, sz, cs, out);
}

// Round 14
// 135.836 us; speedup vs baseline: 1.0515x; 1.0515x over previous
//
#include <hip/hip_runtime.h>
#include <hip/hip_bf16.h>

// 3D bilateral filter, radius 2 (125 taps), input (2,1,128,128,128) f32.
// v14: v12 body exactly; only change lb(256,4) -> lb(256,6) to raise the
// resident-wave cap and cover the ~11% stall gap (wall 126k vs busy 112k
// cyc/SIMD). VGPR budget 512/6=85 vs live set ~40 -> no spill expected
// (WRITE_SIZE must stay 16384 KB; v10/v13 showed spills at tight budgets).
// Closed cycle model (fits v3..v13, ~1.6 GHz sustained): scalar VALU 2 cyc,
// v_cvt_u32_f32 4, v_exp_f32 ~9, VOP3P 4. Tap = 12 cyc irreducible:
//   sub(2) fma(t,-t,CC)(2) sat-cvt(4) add(2) fma(2).
// Coarsening beyond 4 voxels/thread spills (v6/v10/v13) — don't.
// Tile pre-scaled by sR; OOB sentinel -> -inf -> cvt saturates -> w=+0.

#define RADIUS 2
#define N 128
#define TX 16
#define TY 8
#define TZ 8
#define PITCH (TX + 2 * RADIUS)      // 20 floats per row (16B-aligned rows)
#define LYD (TY + 2 * RADIUS)        // 12
#define LZD (TZ + 2 * RADIUS)        // 12
#define LDS_SIZE (PITCH * LYD * LZD) // 2880 floats = 11.25 KB

#define LOG2E 1.4426950408889634f
#define BIG 1.0e18f
#define EXP2_SCALE 8388608.0f        // 2^23
#define EXP2_BIAS 1065353216.0f      // 127 * 2^23

__global__ __launch_bounds__(256, 6) void bilateral3d_kernel(
    const float* __restrict__ in, const float* __restrict__ p_sx,
    const float* __restrict__ p_sy, const float* __restrict__ p_sz,
    const float* __restrict__ p_cs, float* __restrict__ out) {
  __shared__ float s[LDS_SIZE];

  const int tid = threadIdx.x;
  const int x0 = blockIdx.x * TX;
  const int y0 = blockIdx.y * TY;
  const int zb = blockIdx.z;  // low 4 bits = z-tile, bit 4 = batch
  const int z0 = (zb & 15) * TZ;
  const int b = zb >> 4;

  const float sxv = p_sx[0], syv = p_sy[0], szv = p_sz[0], csv = p_cs[0];
  const float AX2 = EXP2_SCALE * LOG2E / (2.0f * sxv * sxv);
  const float AY2 = EXP2_SCALE * LOG2E / (2.0f * syv * syv);
  const float AZ2 = EXP2_SCALE * LOG2E / (2.0f * szv * szv);
  const float AX2_4 = 4.0f * AX2;
  const float sR = __builtin_sqrtf(EXP2_SCALE * LOG2E / (2.0f * csv * csv));

  const float* vol = in + (size_t)b * (N * N * N);

  // --- stage 20x12x12 halo tile, PRE-SCALED by sR (OOB -> sentinel) ---
  for (int i = tid; i < LDS_SIZE; i += 256) {
    int lx = i % PITCH;
    int t = i / PITCH;
    int ly = t % LYD;
    int lz = t / LYD;
    int gx = x0 + lx - RADIUS;
    int gy = y0 + ly - RADIUS;
    int gz = z0 + lz - RADIUS;
    float v = BIG;
    if ((unsigned)gx < N && (unsigned)gy < N && (unsigned)gz < N)
      v = vol[((size_t)gz * N + gy) * N + gx];
    s[i] = v * sR;
  }
  __syncthreads();

  // lane decode: ty fast (v12 remap; conflict-minimal within octets)
  const int ty = tid & 7;
  const int tx = (tid >> 3) & 3;  // x-group: voxels x0+4tx .. x0+4tx+3
  const int tz = tid >> 5;

  const int xw = 4 * tx;  // word offset within row of this thread's tap window

  // centers (scaled): words [xw+2 .. xw+5] of the (dz=0,dy=0) row
  const int cbase = ((tz + RADIUS) * LYD + (ty + RADIUS)) * PITCH + xw;
  const float4 CA = *(const float4*)&s[cbase];
  const float4 CB = *(const float4*)&s[cbase + 4];
  const float xc0 = CA.z, xc1 = CA.w, xc2 = CB.x, xc3 = CB.y;

  float n0 = 0, n1 = 0, n2 = 0, n3 = 0;
  float e0 = 0, e1 = 0, e2 = 0, e3 = 0;  // denominators

  // scalar Schraudolph tap: 5 insts / 12 cyc
#define TAP(XC, FV, CC, NN, DD)                          \
  {                                                      \
    float _t = (XC) - (FV);                              \
    float _f = fmaf(_t, -_t, (CC));                      \
    unsigned _q;                                         \
    asm("v_cvt_u32_f32 %0, %1" : "=v"(_q) : "v"(_f));    \
    float _w = __uint_as_float(_q);                      \
    DD += _w;                                            \
    NN = fmaf(_w, (FV), NN);                             \
  }

#pragma unroll 1
  for (int dz = -RADIUS; dz <= RADIUS; ++dz) {
    const float pz2 = AZ2 * (float)(dz * dz);
    const int zrow = (tz + RADIUS + dz) * LYD;
#pragma unroll
    for (int dy = -RADIUS; dy <= RADIUS; ++dy) {
      const float cc0 = EXP2_BIAS - (pz2 + AY2 * (float)(dy * dy));
      const float cm1 = cc0 - AX2;    // |dx| = 1
      const float cm4 = cc0 - AX2_4;  // |dx| = 2
      const int rb = (zrow + (ty + RADIUS + dy)) * PITCH + xw;
      const float4 A = *(const float4*)&s[rb];
      const float4 B = *(const float4*)&s[rb + 4];
      const float f0 = A.x, f1 = A.y, f2 = A.z, f3 = A.w;
      const float f4 = B.x, f5 = B.y, f6 = B.z, f7 = B.w;

      // dx = -2
      TAP(xc0, f0, cm4, n0, e0)
      TAP(xc1, f1, cm4, n1, e1)
      TAP(xc2, f2, cm4, n2, e2)
      TAP(xc3, f3, cm4, n3, e3)
      // dx = -1
      TAP(xc0, f1, cm1, n0, e0)
      TAP(xc1, f2, cm1, n1, e1)
      TAP(xc2, f3, cm1, n2, e2)
      TAP(xc3, f4, cm1, n3, e3)
      // dx = 0
      TAP(xc0, f2, cc0, n0, e0)
      TAP(xc1, f3, cc0, n1, e1)
      TAP(xc2, f4, cc0, n2, e2)
      TAP(xc3, f5, cc0, n3, e3)
      // dx = +1
      TAP(xc0, f3, cm1, n0, e0)
      TAP(xc1, f4, cm1, n1, e1)
      TAP(xc2, f5, cm1, n2, e2)
      TAP(xc3, f6, cm1, n3, e3)
      // dx = +2
      TAP(xc0, f4, cm4, n0, e0)
      TAP(xc1, f5, cm4, n1, e1)
      TAP(xc2, f6, cm4, n2, e2)
      TAP(xc3, f7, cm4, n3, e3)
    }
  }

  // values were pre-scaled by sR: out = num / (den * sR)
  float4 r;
  r.x = n0 / (e0 * sR);
  r.y = n1 / (e1 * sR);
  r.z = n2 / (e2 * sR);
  r.w = n3 / (e3 * sR);

  const int gz = z0 + tz, gy = y0 + ty;
  *(float4*)&out[(((size_t)b * N + gz) * N + gy) * N + (x0 + xw)] = r;
}

extern "C" void kernel_launch(void* const* d_in, const int* in_sizes, int n_in,
                              void* d_out, int out_size, void* d_ws, size_t ws_size,
                              hipStream_t stream) {
  const float* in = (const float*)d_in[0];
  const float* sx = (const float*)d_in[1];
  const float* sy = (const float*)d_in[2];
  const float* sz = (const float*)d_in[3];
  const float* cs = (const float*)d_in[4];
  float* out = (float*)d_out;

  dim3 grid(N / TX, N / TY, (N / TZ) * 2);  // 8 x 16 x 32
  bilateral3d_kernel<<<grid, 256, 0, stream>>>(in, sx, sy, sz, cs, out);
}